// Round 1
// 426.918 us; speedup vs baseline: 1.1014x; 1.1014x over previous
//
#include <hip/hip_runtime.h>
#include <hip/hip_bf16.h>
#include <math.h>

// BiMambaEncoderLayer: B=2, L=2048, D_MODEL=512, ED=1024, N=16, DCONV=4,
// DT_RANK=32, D_FF=1024. f32 in/out.
// Round-16: scan5_k -> scan6_k. The scan was latency-bound (VALUBusy 47%,
// HBM 4%, occupancy 21.6%): 256-iter serial chunk-scan on 16/256 threads,
// dA exps computed twice (272 exp/thread), 33KB LDS capping 4 blocks/CU.
// scan6 keeps per-chunk affine partials (S[8],P[8]) in registers -> single
// walk (128 exp/thread, B/C loaded once), Kogge-Stone affine scan across all
// 256 lanes (shfl intra-wave + 4-entry LDS cross-wave), LDS < 1KB.
// Everything else unchanged from round-15. 12 dispatches, 46 MiB workspace.

#define BD 2
#define LD 2048
#define DMODEL 512
#define EDIM 1024
#define NST 16
#define DTR 32
#define DFF 1024
#define MROWS (BD*LD)   // 4096

typedef __hip_bfloat16 bf16;
typedef __bf16 bf16x8 __attribute__((ext_vector_type(8)));
typedef float  f32x4  __attribute__((ext_vector_type(4)));

__device__ __forceinline__ float sig_(float x) { return 1.f / (1.f + __expf(-x)); }

// ---------------- prep: all weight transposes + x->bf16, one dispatch --------
// blocks [0,2048): xconv | [2048,4096): inwT f/b | [4096,5120): outwT f/b |
// [5120,5632): fw1T | [5632,6144): fw2T
__global__ __launch_bounds__(256)
void prep_k(const float* __restrict__ x, bf16* __restrict__ xbf,
            const float* __restrict__ inw_f, const float* __restrict__ inw_b,
            bf16* __restrict__ inwT,
            const float* __restrict__ outw_f, const float* __restrict__ outw_b,
            bf16* __restrict__ outwT,
            const float* __restrict__ fw1, bf16* __restrict__ fw1T,
            const float* __restrict__ fw2, bf16* __restrict__ fw2T)
{
    const int bid = blockIdx.x, tid = threadIdx.x;
    if (bid < 2048) {
        size_t i = (size_t)bid * 1024 + tid * 4;
        float4 v = *(const float4*)(x + i);
        bf16* o = xbf + i;
        o[0] = __float2bfloat16(v.x); o[1] = __float2bfloat16(v.y);
        o[2] = __float2bfloat16(v.z); o[3] = __float2bfloat16(v.w);
        return;
    }
    const float* W; bf16* WT; int R, C, cx, ry;
    if (bid < 4096) {
        int d = (bid - 2048) >> 10, t = (bid - 2048) & 1023;
        W = d ? inw_b : inw_f; WT = inwT + (size_t)d * 2048 * 512;
        R = 512; C = 2048; cx = t & 63; ry = t >> 6;
    } else if (bid < 5120) {
        int d = (bid - 4096) >> 9, t = (bid - 4096) & 511;
        W = d ? outw_b : outw_f; WT = outwT + (size_t)d * 512 * 1024;
        R = 1024; C = 512; cx = t & 15; ry = t >> 4;
    } else if (bid < 5632) {
        int t = bid - 5120; W = fw1; WT = fw1T; R = 512; C = 1024;
        cx = t & 31; ry = t >> 5;
    } else {
        int t = bid - 5632; W = fw2; WT = fw2T; R = 1024; C = 512;
        cx = t & 15; ry = t >> 4;
    }
    __shared__ float tt[32][33];
    const int c0 = cx * 32, r0 = ry * 32;
    const int col = tid & 31, rr = tid >> 5;
#pragma unroll
    for (int p = 0; p < 4; ++p)
        tt[p * 8 + rr][col] = W[(size_t)(r0 + p * 8 + rr) * C + c0 + col];
    __syncthreads();
#pragma unroll
    for (int p = 0; p < 4; ++p)
        WT[(size_t)(c0 + p * 8 + rr) * R + r0 + col] =
            __float2bfloat16(tt[col][p * 8 + rr]);
}

// ---------------- dir-merged bf16 MFMA GEMM ----------------------------------
// A[M][K] bf16 (per-dir offset Astr, or FLIPD1 row-flip for dir1),
// BT[N][K] bf16 (per-dir offset Bstr). MODE: 0 plain bf16; 2 relu+bias bf16;
// 3 out=v+bias+mp; 4 out+=v+bias+mp (mp bf16, per-dir mpStr).
template<int BM, int BN, int MODE, bool FLIPD1>
__global__ __launch_bounds__(256)
void bgemm2_k(const bf16* __restrict__ A, size_t Astr, int lda,
              const bf16* __restrict__ BT, size_t Bstr,
              const float* __restrict__ bias,
              bf16* __restrict__ Cb, size_t Cstr, int ldc,
              const bf16* __restrict__ mp, size_t mpStr,
              float* __restrict__ outp,
              int M, int N, int K, int zoff)
{
    constexpr int FRm = BM / 32, FRn = BN / 32;
    __shared__ __align__(16) bf16 As[BM][40];
    __shared__ __align__(16) bf16 Bs[BN][40];
    const int tid = threadIdx.x;
    const int dir = blockIdx.z + zoff;
    const bool flip = FLIPD1 && (dir == 1);
    const bf16* Ad = A + (size_t)dir * Astr;
    const bf16* Bd = BT + (size_t)dir * Bstr;
    bf16* Cd = Cb ? Cb + (size_t)dir * Cstr : nullptr;
    const bf16* mpd = mp ? mp + (size_t)dir * mpStr : nullptr;
    const int bm = blockIdx.y * BM, bn = blockIdx.x * BN;
    const int wave = tid >> 6, lane = tid & 63;
    const int wm = (wave >> 1) * (BM / 2), wn = (wave & 1) * (BN / 2);
    const int lm = lane & 15, lq = lane >> 4;
    f32x4 acc[FRm][FRn] = {};

    for (int k0 = 0; k0 < K; k0 += 32) {
#pragma unroll
        for (int p = 0; p < BM / 64; ++p) {
            int row = p * 64 + (tid >> 2), col = (tid & 3) * 8;
            int gm = bm + row;
            if (flip) gm = (gm & ~(LD - 1)) + (LD - 1 - (gm & (LD - 1)));
            *(bf16x8*)&As[row][col] =
                *(const bf16x8*)(Ad + (size_t)gm * lda + k0 + col);
        }
#pragma unroll
        for (int p = 0; p < BN / 64; ++p) {
            int row = p * 64 + (tid >> 2), col = (tid & 3) * 8;
            *(bf16x8*)&Bs[row][col] =
                *(const bf16x8*)(Bd + (size_t)(bn + row) * K + k0 + col);
        }
        __syncthreads();

        bf16x8 af[FRm], bfr[FRn];
#pragma unroll
        for (int i = 0; i < FRm; ++i)
            af[i] = *(const bf16x8*)&As[wm + 16 * i + lm][lq * 8];
#pragma unroll
        for (int j = 0; j < FRn; ++j)
            bfr[j] = *(const bf16x8*)&Bs[wn + 16 * j + lm][lq * 8];
#pragma unroll
        for (int i = 0; i < FRm; ++i)
#pragma unroll
            for (int j = 0; j < FRn; ++j)
                acc[i][j] = __builtin_amdgcn_mfma_f32_16x16x32_bf16(
                    af[i], bfr[j], acc[i][j], 0, 0, 0);
        __syncthreads();
    }

#pragma unroll
    for (int i = 0; i < FRm; ++i) {
#pragma unroll
        for (int j = 0; j < FRn; ++j) {
            int col = bn + wn + 16 * j + lm;
            float bv = (MODE >= 2) ? bias[col] : 0.f;
#pragma unroll
            for (int r = 0; r < 4; ++r) {
                int row = bm + wm + 16 * i + lq * 4 + r;
                float v = acc[i][j][r] + bv;
                size_t idx = (size_t)row * ldc + col;
                if (MODE == 0)      Cd[idx] = __float2bfloat16(v);
                else if (MODE == 2) Cd[idx] = __float2bfloat16(fmaxf(v, 0.f));
                else if (MODE == 3) outp[idx] = v + __bfloat162float(mpd[idx]);
                else                outp[idx] += v + __bfloat162float(mpd[idx]);
            }
        }
    }
}

// ---------------- zgate: yrow = silu(x(flip?) @ inw_z) * y2t^T ---------------
// 64x128 GEMM (M=4096 rows, N=1024 e, K=512); epilogue stages y2t tile
// [128 e][64 l] -> LDS sy[l][e] (native __bf16) then gates.
__global__ __launch_bounds__(256)
void zgate_k(const bf16* __restrict__ xbf, const bf16* __restrict__ inwT,
             const bf16* __restrict__ y2t_all, bf16* __restrict__ yrow_all)
{
    __shared__ __align__(16) bf16 As[64][40];
    __shared__ __align__(16) bf16 Bs[128][40];
    __shared__ __bf16 sy[64][130];
    const int tid = threadIdx.x;
    const int dir = blockIdx.z;
    const bf16* Bd = inwT + (size_t)dir * (2048 * 512) + (size_t)1024 * 512;
    const bf16* y2t = y2t_all + (size_t)dir * ((size_t)MROWS * EDIM);
    bf16* yrow = yrow_all + (size_t)dir * ((size_t)MROWS * EDIM);
    const int bm = blockIdx.y * 64, bn = blockIdx.x * 128;
    const int wave = tid >> 6, lane = tid & 63;
    const int wm = (wave >> 1) * 32, wn = (wave & 1) * 64;
    const int lm = lane & 15, lq = lane >> 4;
    f32x4 acc[2][4] = {};

    for (int k0 = 0; k0 < 512; k0 += 32) {
        {
            int row = tid >> 2, col = (tid & 3) * 8;
            int gm = bm + row;
            if (dir == 1) gm = (gm & ~(LD - 1)) + (LD - 1 - (gm & (LD - 1)));
            *(bf16x8*)&As[row][col] =
                *(const bf16x8*)(xbf + (size_t)gm * 512 + k0 + col);
        }
#pragma unroll
        for (int p = 0; p < 2; ++p) {
            int row = p * 64 + (tid >> 2), col = (tid & 3) * 8;
            *(bf16x8*)&Bs[row][col] =
                *(const bf16x8*)(Bd + (size_t)(bn + row) * 512 + k0 + col);
        }
        __syncthreads();
        bf16x8 af[2], bfr[4];
#pragma unroll
        for (int i = 0; i < 2; ++i)
            af[i] = *(const bf16x8*)&As[wm + 16 * i + lm][lq * 8];
#pragma unroll
        for (int j = 0; j < 4; ++j)
            bfr[j] = *(const bf16x8*)&Bs[wn + 16 * j + lm][lq * 8];
#pragma unroll
        for (int i = 0; i < 2; ++i)
#pragma unroll
            for (int j = 0; j < 4; ++j)
                acc[i][j] = __builtin_amdgcn_mfma_f32_16x16x32_bf16(
                    af[i], bfr[j], acc[i][j], 0, 0, 0);
        __syncthreads();
    }

    // stage y2t tile: e in [bn,bn+128), l in [bm&2047 .. +64), batch b=bm>>11
    {
        const int b = bm >> 11, l0 = bm & (LD - 1);
        int e = tid >> 1, lh = (tid & 1) * 32;
        const bf16* yp = y2t + ((size_t)b * EDIM + bn + e) * LD + l0 + lh;
#pragma unroll
        for (int i = 0; i < 4; ++i) {
            bf16x8 v = *(const bf16x8*)(yp + i * 8);
#pragma unroll
            for (int j = 0; j < 8; ++j) sy[lh + i * 8 + j][e] = v[j];
        }
    }
    __syncthreads();
#pragma unroll
    for (int i = 0; i < 2; ++i) {
#pragma unroll
        for (int j = 0; j < 4; ++j) {
            int col = bn + wn + 16 * j + lm;
#pragma unroll
            for (int r = 0; r < 4; ++r) {
                int row = bm + wm + 16 * i + lq * 4 + r;
                float z = acc[i][j][r];
                float g = z * sig_(z);
                float y = (float)sy[(row - bm)][col - bn];
                yrow[(size_t)row * EDIM + col] = __float2bfloat16(g * y);
            }
        }
    }
}

// ---------------- conv(4)+bias+silu+transpose, dir-merged --------------------
__global__ __launch_bounds__(256)
void conv2_k(const bf16* __restrict__ xs2,
             const float* __restrict__ cw_f, const float* __restrict__ cb_f,
             const float* __restrict__ cw_b, const float* __restrict__ cb_b,
             bf16* __restrict__ xct2)
{
    __shared__ float sxs[67][64];
    __shared__ float sout[64][65];
    const int tid = threadIdx.x;
    const int dir = blockIdx.z;
    const bf16* xs = xs2 + (size_t)dir * ((size_t)MROWS * EDIM);
    const float* w  = dir ? cw_b : cw_f;
    const float* cb = dir ? cb_b : cb_f;
    bf16* xct = xct2 + (size_t)dir * ((size_t)MROWS * EDIM);
    const int e0 = blockIdx.x * 64;
    const int bl0 = blockIdx.y * 64;
    const int lloc0 = bl0 & (LD - 1);
    const int b = bl0 >> 11;
    {
        int row4 = tid >> 6, col = tid & 63;
#pragma unroll
        for (int i = 0; i < 17; ++i) {
            int hr = i * 4 + row4;
            if (hr < 67) {
                int lr = lloc0 + hr - 3;
                sxs[hr][col] = (lr >= 0)
                    ? __bfloat162float(xs[(size_t)(bl0 + hr - 3) * EDIM + e0 + col]) : 0.f;
            }
        }
    }
    __syncthreads();
    {
        int lr4 = tid >> 6, e = tid & 63;
        float w0 = w[(e0 + e) * 4 + 0], w1 = w[(e0 + e) * 4 + 1];
        float w2 = w[(e0 + e) * 4 + 2], w3 = w[(e0 + e) * 4 + 3];
        float cbv = cb[e0 + e];
#pragma unroll
        for (int i = 0; i < 16; ++i) {
            int lr = i * 4 + lr4;
            float acc = cbv;
            acc = fmaf(sxs[lr + 0][e], w0, acc);
            acc = fmaf(sxs[lr + 1][e], w1, acc);
            acc = fmaf(sxs[lr + 2][e], w2, acc);
            acc = fmaf(sxs[lr + 3][e], w3, acc);
            sout[e][lr] = acc * sig_(acc);
        }
    }
    __syncthreads();
    {
        int er4 = tid >> 6, l = tid & 63;
#pragma unroll
        for (int i = 0; i < 16; ++i) {
            int er = i * 4 + er4;
            xct[((size_t)b * EDIM + e0 + er) * LD + lloc0 + l] =
                __float2bfloat16(sout[er][l]);
        }
    }
}

// ---------------- G2 dir-merged: dbl_t = (xc^T @ xproj)^T --------------------
__global__ __launch_bounds__(256)
void g2_k(const bf16* __restrict__ xct2, const float* __restrict__ xp_f,
          const float* __restrict__ xp_b, float* __restrict__ dblt2)
{
    __shared__ __align__(16) float As[32][18];
    __shared__ __align__(16) float Bs[32][66];
    const int tid = threadIdx.x;
    const int dir = blockIdx.y;
    const bf16* xct = xct2 + (size_t)dir * ((size_t)MROWS * EDIM);
    const float* xproj = dir ? xp_b : xp_f;
    float* dblt = dblt2 + (size_t)dir * (2 * 64 * LD);
    const int r0 = blockIdx.x * 16;
    const int bB = r0 >> 11, l0 = r0 & (LD - 1);
    const int row = tid >> 4, col4 = (tid & 15) * 4;
    float acc[4] = {};

    for (int k0 = 0; k0 < EDIM; k0 += 32) {
        {
            int k = tid >> 3, ls = (tid & 7) * 2;
            const bf16* p = xct + ((size_t)bB * EDIM + k0 + k) * LD + l0 + ls;
            As[k][ls] = __bfloat162float(p[0]);
            As[k][ls + 1] = __bfloat162float(p[1]);
        }
        {
            int k = tid >> 3, ns = (tid & 7) * 8;
            const float* p = xproj + (size_t)(k0 + k) * 64 + ns;
            float4 v0 = *(const float4*)p, v1 = *(const float4*)(p + 4);
            float* d = &Bs[k][ns];
            d[0]=v0.x; d[1]=v0.y; d[2]=v0.z; d[3]=v0.w;
            d[4]=v1.x; d[5]=v1.y; d[6]=v1.z; d[7]=v1.w;
        }
        __syncthreads();
#pragma unroll
        for (int kk = 0; kk < 32; ++kk) {
            float a = As[kk][row];
            float4 b4 = *(const float4*)&Bs[kk][col4];
            acc[0] = fmaf(a, b4.x, acc[0]);
            acc[1] = fmaf(a, b4.y, acc[1]);
            acc[2] = fmaf(a, b4.z, acc[2]);
            acc[3] = fmaf(a, b4.w, acc[3]);
        }
        __syncthreads();
    }
#pragma unroll
    for (int j = 0; j < 4; ++j)
        dblt[((size_t)bB * 64 + col4 + j) * LD + l0 + row] = acc[j];
}

// ---------------- G3 dir-merged: dlt_t(bf16) = softplus(...)^T ---------------
__global__ __launch_bounds__(256)
void g3_k(const float* __restrict__ dblt2,
          const float* __restrict__ dtw_f, const float* __restrict__ dtb_f,
          const float* __restrict__ dtw_b, const float* __restrict__ dtb_b,
          bf16* __restrict__ dltt2)
{
    __shared__ __align__(16) float As[16][68];
    __shared__ __align__(16) float Bs[16][68];
    const int tid = threadIdx.x;
    const int dir = blockIdx.z;
    const float* Ap = dblt2 + (size_t)dir * (2 * 64 * LD);
    const float* Bw = dir ? dtw_b : dtw_f;
    const float* bias = dir ? dtb_b : dtb_f;
    bf16* Ct = dltt2 + (size_t)dir * ((size_t)MROWS * EDIM);
    const int bm = blockIdx.y * 64;
    const int bn = blockIdx.x * 64;
    const int bB = bm >> 11, l0 = bm & (LD - 1);
    const int tx = tid & 15, ty = tid >> 4;
    float acc[4][4] = {};

    for (int k0 = 0; k0 < DTR; k0 += 16) {
#pragma unroll
        for (int i = 0; i < 4; ++i) {
            int k = i * 4 + (tid >> 6), ll = tid & 63;
            As[k][ll] = Ap[((size_t)bB * 64 + k0 + k) * LD + l0 + ll];
        }
#pragma unroll
        for (int i = 0; i < 4; ++i) {
            int idx = tid + 256 * i;
            int nl = idx & 63, kl = idx >> 6;
            Bs[kl][nl] = Bw[(size_t)(k0 + kl) * EDIM + bn + nl];
        }
        __syncthreads();
#pragma unroll
        for (int kk = 0; kk < 16; ++kk) {
            float4 av = *(const float4*)&As[kk][ty * 4];
            float4 bv = *(const float4*)&Bs[kk][tx * 4];
            float a[4] = {av.x, av.y, av.z, av.w};
            float b[4] = {bv.x, bv.y, bv.z, bv.w};
#pragma unroll
            for (int i = 0; i < 4; ++i)
#pragma unroll
                for (int j = 0; j < 4; ++j)
                    acc[i][j] = fmaf(a[i], b[j], acc[i][j]);
        }
        __syncthreads();
    }
#pragma unroll
    for (int i = 0; i < 4; ++i) {
        int r = bm + ty * 4 + i;
#pragma unroll
        for (int j = 0; j < 4; ++j) {
            int c = bn + tx * 4 + j;
            float v = acc[i][j] + bias[c];
            v = (v > 20.f) ? v : log1pf(__expf(v));
            Ct[((size_t)(r >> 11) * EDIM + c) * LD + (r & (LD - 1))] =
                __float2bfloat16(v);
        }
    }
}

// ---------------- scan6 dir-merged: 256 chunks x 8 steps, parallel scan ------
// Per block: one (dir, batch, e) channel. Each of 256 threads owns an 8-step
// chunk; keeps affine partials S[l] (local state, h_init=0) and P[l]
// (cumprod dA) in registers. Inter-chunk composition is a Kogge-Stone affine
// scan: 6 shfl levels intra-wave + 4-entry LDS compose across the 4 waves.
// Final h_l = S[l] + P[l]*H  -> no second dA walk, B/C rows loaded once.
__global__ __launch_bounds__(256)
void scan6_k(bf16* __restrict__ xct2, const bf16* __restrict__ dltt2,
             const float* __restrict__ dblt2,
             const float* __restrict__ alog_f, const float* __restrict__ alog_b,
             const float* __restrict__ dp_f, const float* __restrict__ dp_b)
{
    __shared__ float sA[NST];
    __shared__ float sWp[NST][4];
    __shared__ float sWs[NST][4];
    const int gid = blockIdx.x;                 // 0..4095
    const int dir = gid >> 11;
    const int bb  = (gid >> 10) & 1;
    const int e   = gid & (EDIM - 1);
    const float* A_log = dir ? alog_b : alog_f;
    const float* Dp    = dir ? dp_b   : dp_f;
    bf16* xct = xct2 + (size_t)dir * ((size_t)MROWS * EDIM);
    const bf16* dltt = dltt2 + (size_t)dir * ((size_t)MROWS * EDIM);
    const float* bt = dblt2 + (size_t)dir * (2 * 64 * LD) + (size_t)bb * 64 * LD;
    const int tid = threadIdx.x;
    const int wave = tid >> 6, lane = tid & 63;
    const size_t baset = ((size_t)bb * EDIM + e) * LD;
    const int l0 = tid * 8;

    if (tid < NST) sA[tid] = -__expf(A_log[e * NST + tid]);

    float xv[8], dv[8], dx[8];
    {
        bf16x8 xr = *(const bf16x8*)(xct + baset + l0);
        bf16x8 dr = *(const bf16x8*)(dltt + baset + l0);
#pragma unroll
        for (int j = 0; j < 8; ++j) { xv[j] = (float)xr[j]; dv[j] = (float)dr[j]; }
    }
#pragma unroll
    for (int j = 0; j < 8; ++j) dx[j] = dv[j] * xv[j];
    __syncthreads();

    float y[8] = {};
    for (int n = 0; n < NST; ++n) {
        const float An = sA[n];
        const float* Bp = bt + (size_t)(DTR + n) * LD + l0;
        const float* Cp = bt + (size_t)(DTR + NST + n) * LD + l0;
        float4 b0 = *(const float4*)Bp, b1 = *(const float4*)(Bp + 4);
        float4 c0 = *(const float4*)Cp, c1 = *(const float4*)(Cp + 4);
        float Br[8] = {b0.x,b0.y,b0.z,b0.w, b1.x,b1.y,b1.z,b1.w};
        float Cr[8] = {c0.x,c0.y,c0.z,c0.w, c1.x,c1.y,c1.z,c1.w};

        // single walk: local state S (h_init=0) and cumprod P, in registers
        float S[8], P[8];
        float h = 0.f, pr = 1.f;
#pragma unroll
        for (int l = 0; l < 8; ++l) {
            float a = __expf(dv[l] * An);
            pr *= a;
            h = fmaf(a, h, dx[l] * Br[l]);
            P[l] = pr; S[l] = h;
        }

        // Kogge-Stone inclusive affine scan across the 64 chunks of this wave
        float p = pr, s = h;
#pragma unroll
        for (int d = 1; d < 64; d <<= 1) {
            float pp = __shfl_up(p, d, 64);
            float sp = __shfl_up(s, d, 64);
            if (lane >= d) { s = fmaf(sp, p, s); p *= pp; }
        }
        // wave totals -> LDS, compose across waves (ascending order)
        if (lane == 63) { sWp[n][wave] = p; sWs[n][wave] = s; }
        __syncthreads();
        float Hoff = 0.f;
#pragma unroll
        for (int w = 0; w < 3; ++w)
            if (w < wave) Hoff = fmaf(sWp[n][w], Hoff, sWs[n][w]);
        // exclusive prefix for this chunk: apply lanes [wavebase..lane-1] to Hoff
        float pprev = __shfl_up(p, 1, 64);
        float sprev = __shfl_up(s, 1, 64);
        float H = (lane == 0) ? Hoff : fmaf(pprev, Hoff, sprev);

#pragma unroll
        for (int l = 0; l < 8; ++l)
            y[l] = fmaf(Cr[l], fmaf(P[l], H, S[l]), y[l]);
    }

    const float Dv = Dp[e];
    bf16x8 o;
#pragma unroll
    for (int l = 0; l < 8; ++l) o[l] = (__bf16)fmaf(xv[l], Dv, y[l]);
    *(bf16x8*)(xct + baset + l0) = o;
}

// ---------------- layernorm (bf16 in-place), dir0 rows only ------------------
__global__ __launch_bounds__(256)
void ln_k(bf16* __restrict__ m, const float* __restrict__ gg,
          const float* __restrict__ bb)
{
    int row = (blockIdx.x * 256 + threadIdx.x) >> 6;
    int lane = threadIdx.x & 63;
    bf16* r = m + (size_t)row * DMODEL;
    float v[8], s = 0.f, s2 = 0.f;
#pragma unroll
    for (int i = 0; i < 8; ++i) {
        v[i] = __bfloat162float(r[lane + 64 * i]);
        s += v[i]; s2 = fmaf(v[i], v[i], s2);
    }
#pragma unroll
    for (int off = 32; off >= 1; off >>= 1) {
        s  += __shfl_xor(s, off, 64);
        s2 += __shfl_xor(s2, off, 64);
    }
    float mu = s * (1.f / DMODEL);
    float var = s2 * (1.f / DMODEL) - mu * mu;
    float inv = rsqrtf(var + 1e-5f);
#pragma unroll
    for (int i = 0; i < 8; ++i)
        r[lane + 64 * i] = __float2bfloat16(
            (v[i] - mu) * inv * gg[lane + 64 * i] + bb[lane + 64 * i]);
}

__global__ void sentinel_k(float* __restrict__ o)
{
    int i = blockIdx.x * 256 + threadIdx.x;
    o[i] = 100.0f;
}

extern "C" void kernel_launch(void* const* d_in, const int* in_sizes, int n_in,
                              void* d_out, int out_size, void* d_ws, size_t ws_size,
                              hipStream_t stream)
{
    const float* x    = (const float*)d_in[0];
    const float* n1g  = (const float*)d_in[19];
    const float* n1b  = (const float*)d_in[20];
    const float* fw1  = (const float*)d_in[23];
    const float* fb1  = (const float*)d_in[24];
    const float* fw2  = (const float*)d_in[25];
    const float* fb2  = (const float*)d_in[26];
    float* out = (float*)d_out;

    const size_t MiB = 1024 * 1024;
    const size_t SZ_DM = (size_t)MROWS * DMODEL;
    if (ws_size < 46 * MiB) {
        sentinel_k<<<dim3(SZ_DM / 256), dim3(256), 0, stream>>>(out);
        return;
    }

    // ---- 46 MiB layout ----
    char* base = (char*)d_ws;
    bf16* fw1T  = (bf16*)base;                 // [1024][512]        1 MiB
    bf16* fw2T  = (bf16*)(base + 1 * MiB);     // [512][1024]        1 MiB
    bf16* outwT = (bf16*)(base + 2 * MiB);     // [2][512][1024]     2 MiB
    bf16* inwT  = (bf16*)(base + 4 * MiB);     // [2][2048][512]     4 MiB
    bf16* xbf   = (bf16*)(base + 8 * MiB);     // [4096][512]        4 MiB (live thru zgate)
    char* RA    = base + 12 * MiB;             // 16 MiB: xs2 -> dltt2 -> yrow2 -> ffh2
    bf16* xs2   = (bf16*)RA;                   // [2][4096][1024]
    bf16* dltt2 = (bf16*)RA;
    bf16* yrow2 = (bf16*)RA;
    bf16* ffh2  = (bf16*)RA;
    char* RB    = base + 28 * MiB;             // 16 MiB: xct2 -> mbf2(8)
    bf16* xct2  = (bf16*)RB;                   // [2][2][1024][2048]
    bf16* mbf2  = (bf16*)RB;                   // [2][4096][512]
    float* dblt2 = (float*)(base + 44 * MiB);  // [2][2][64][2048]   2 MiB

    const float* inw_f  = (const float*)d_in[1];
    const float* cw_f   = (const float*)d_in[2];
    const float* cb_f   = (const float*)d_in[3];
    const float* xp_f   = (const float*)d_in[4];
    const float* dtw_f  = (const float*)d_in[5];
    const float* dtb_f  = (const float*)d_in[6];
    const float* alog_f = (const float*)d_in[7];
    const float* dp_f   = (const float*)d_in[8];
    const float* outw_f = (const float*)d_in[9];
    const float* inw_b  = (const float*)d_in[10];
    const float* cw_b   = (const float*)d_in[11];
    const float* cb_b   = (const float*)d_in[12];
    const float* xp_b   = (const float*)d_in[13];
    const float* dtw_b  = (const float*)d_in[14];
    const float* dtb_b  = (const float*)d_in[15];
    const float* alog_b = (const float*)d_in[16];
    const float* dp_b   = (const float*)d_in[17];
    const float* outw_b = (const float*)d_in[18];

    dim3 blk(256);
    const size_t U = (size_t)MROWS * EDIM;   // 4,194,304 elems

    // 1. prep: all transposes + xconv
    prep_k<<<dim3(6144), blk, 0, stream>>>(x, xbf, inw_f, inw_b, inwT,
                                           outw_f, outw_b, outwT,
                                           fw1, fw1T, fw2, fw2T);
    // 2. G1: xs2[dir] = x(flip d1) @ in_w[:, :1024]
    bgemm2_k<64, 128, 0, true><<<dim3(8, 64, 2), blk, 0, stream>>>(
        xbf, 0, DMODEL, inwT, (size_t)2048 * 512, nullptr,
        xs2, U, EDIM, nullptr, 0, nullptr, MROWS, EDIM, DMODEL, 0);
    // 3. conv + silu + transpose
    conv2_k<<<dim3(16, 64, 2), blk, 0, stream>>>(xs2, cw_f, cb_f, cw_b, cb_b, xct2);
    // 4. G2
    g2_k<<<dim3(256, 2), blk, 0, stream>>>(xct2, xp_f, xp_b, dblt2);
    // 5. G3 (writes dltt2 over dead xs2)
    g3_k<<<dim3(16, 64, 2), blk, 0, stream>>>(dblt2, dtw_f, dtb_f, dtw_b, dtb_b, dltt2);
    // 6. scan (in-place over xct2) — parallel-scan rewrite
    scan6_k<<<dim3(4096), blk, 0, stream>>>(xct2, dltt2, dblt2,
                                            alog_f, alog_b, dp_f, dp_b);
    // 7. zgate: yrow2 = silu(x @ inw_z) * y  (writes over dead dltt2)
    zgate_k<<<dim3(8, 64, 2), blk, 0, stream>>>(xbf, inwT, xct2, yrow2);
    // 8. G4: mbf2[dir] = y @ out_w  (writes over dead xct2)
    bgemm2_k<64, 64, 0, false><<<dim3(8, 64, 2), blk, 0, stream>>>(
        yrow2, U, EDIM, outwT, (size_t)512 * 1024, nullptr,
        mbf2, SZ_DM, DMODEL, nullptr, 0, nullptr, MROWS, DMODEL, EDIM, 0);
    // 9. LN on dir0 half of mbf2 (in place)
    ln_k<<<dim3(MROWS / 4), blk, 0, stream>>>(mbf2, n1g, n1b);
    // 10. G5: ffh2[dir] = relu(m @ fw1 + fb1)  (writes over dead yrow2)
    bgemm2_k<64, 128, 2, false><<<dim3(8, 64, 2), blk, 0, stream>>>(
        mbf2, SZ_DM, DMODEL, fw1T, 0, fb1,
        ffh2, U, DFF, nullptr, 0, nullptr, MROWS, DFF, DMODEL, 0);
    // 11. G6 dir0: out = ffh@fw2 + fb2 + m_f
    bgemm2_k<64, 64, 3, false><<<dim3(8, 64, 1), blk, 0, stream>>>(
        ffh2, U, DFF, fw2T, 0, fb2,
        nullptr, 0, DMODEL, mbf2, SZ_DM, out, MROWS, DMODEL, DFF, 0);
    // 12. G6 dir1: out += ffh@fw2 + fb2 + m_b
    bgemm2_k<64, 64, 4, false><<<dim3(8, 64, 1), blk, 0, stream>>>(
        ffh2, U, DFF, fw2T, 0, fb2,
        nullptr, 0, DMODEL, mbf2, SZ_DM, out, MROWS, DMODEL, DFF, 1);
}